// Round 2
// baseline (116.397 us; speedup 1.0000x reference)
//
#include <hip/hip_runtime.h>

// Chamfer distance, B=16, N=M=4096, D=3, fp32.
// loss = (sum of all 2*16*4096 directional min-d2) / 4096
// d2 = 2*( f + (e - s.t) ),  f=0.5|s|^2, e=0.5|t|^2
// Inner: 3 fma per pair + 2 v_min3 per 4 pairs = 3.5 VALU ops/pair.
// Fused final reduction via decoupled last-block tickets (device atomics).

#define BATCH   16
#define NPTS    4096
#define TPB     256
#define PPT     4                     // query points per thread
#define CHUNK   (PPT * TPB)           // 1024
#define NCHUNK  (NPTS / CHUNK)        // 4
#define SEG     256                   // target points staged per block
#define NSEG    (NPTS / SEG)          // 16
#define NCHUNKS_TOTAL (2 * BATCH * NCHUNK)   // 128
#define NMINS   (2 * BATCH * NPTS)    // 131072

__global__ __launch_bounds__(TPB, 8) void chamfer_kernel(
    const float* __restrict__ src, const float* __restrict__ tgt,
    unsigned int* __restrict__ mins, float* __restrict__ acc,
    unsigned int* __restrict__ cctr, unsigned int* __restrict__ gctr,
    float* __restrict__ out)
{
    __shared__ float4 sh[SEG];        // (x, y, z, 0.5*|t|^2)
    __shared__ int islast;
    __shared__ float wsum[TPB / 64];

    int bx = blockIdx.x;
    const int seg   = bx & (NSEG - 1);   bx >>= 4;
    const int chunk = bx & (NCHUNK - 1); bx >>= 2;
    const int b     = bx & (BATCH - 1);  bx >>= 4;
    const int dir   = bx;

    const float* Abase = (dir ? tgt : src) + (size_t)b * NPTS * 3;  // queries
    const float* Bbase = (dir ? src : tgt) + (size_t)b * NPTS * 3;  // targets

    const int t = threadIdx.x;

    // Stage SEG target points with precomputed 0.5*|t|^2 (1 per thread).
    {
        int p = seg * SEG + t;
        float x = Bbase[3 * p + 0];
        float y = Bbase[3 * p + 1];
        float z = Bbase[3 * p + 2];
        sh[t] = make_float4(x, y, z, 0.5f * (x * x + y * y + z * z));
    }

    // Load PPT query points per thread (stride TPB, coalesced).
    float qx[PPT], qy[PPT], qz[PPT], f[PPT], mn[PPT];
#pragma unroll
    for (int k = 0; k < PPT; k++) {
        int p = chunk * CHUNK + k * TPB + t;
        float x = Abase[3 * p + 0];
        float y = Abase[3 * p + 1];
        float z = Abase[3 * p + 2];
        qx[k] = x; qy[k] = y; qz[k] = z;
        f[k] = 0.5f * (x * x + y * y + z * z);
        mn[k] = 1e30f;
    }

    __syncthreads();

    // Inner loop: 4 targets / iteration. Per k: 12 fma + 2 min3.
    for (int m = 0; m < SEG; m += 4) {
        float4 q0 = sh[m + 0];
        float4 q1 = sh[m + 1];
        float4 q2 = sh[m + 2];
        float4 q3 = sh[m + 3];
#pragma unroll
        for (int k = 0; k < PPT; k++) {
            float a0 = fmaf(-qx[k], q0.x, fmaf(-qy[k], q0.y, fmaf(-qz[k], q0.z, q0.w)));
            float a1 = fmaf(-qx[k], q1.x, fmaf(-qy[k], q1.y, fmaf(-qz[k], q1.z, q1.w)));
            float a2 = fmaf(-qx[k], q2.x, fmaf(-qy[k], q2.y, fmaf(-qz[k], q2.z, q2.w)));
            float a3 = fmaf(-qx[k], q3.x, fmaf(-qy[k], q3.y, fmaf(-qz[k], q3.z, q3.w)));
            // v_min3(a0,a1,a2) then v_min3(that, a3, mn) -> 2 insts
            float m01 = fminf(fminf(a0, a1), a2);
            mn[k] = fminf(fminf(m01, a3), mn[k]);
        }
    }

    // Epilogue: finalize d2 (monotone transform commutes with min), merge.
    const int minsBase = ((dir * BATCH + b) * NPTS) + chunk * CHUNK;
#pragma unroll
    for (int k = 0; k < PPT; k++) {
        float d2 = fmaxf(2.0f * (mn[k] + f[k]), 0.0f);
        atomicMin(&mins[minsBase + k * TPB + t], __float_as_uint(d2));
    }

    __syncthreads();   // all this block's atomics issued & drained (waitcnt)

    const int cid = (dir * BATCH + b) * NCHUNK + chunk;
    if (t == 0) {
        __threadfence();
        unsigned int old = atomicAdd(&cctr[cid], 1u);
        islast = (old == NSEG - 1);
    }
    __syncthreads();
    if (!islast) return;

    // Last block for this chunk: read back the chunk's final mins (via
    // device-scope atomic identity-min reads -> coherent), sum them.
    float s = 0.0f;
#pragma unroll
    for (int k = 0; k < PPT; k++) {
        unsigned int v = atomicMin(&mins[minsBase + k * TPB + t], 0xFFFFFFFFu);
        s += __uint_as_float(v);
    }
#pragma unroll
    for (int off = 32; off > 0; off >>= 1) s += __shfl_down(s, off, 64);
    if ((t & 63) == 0) wsum[t >> 6] = s;
    __syncthreads();
    if (t == 0) {
        float blocksum = wsum[0] + wsum[1] + wsum[2] + wsum[3];
        atomicAdd(acc, blocksum);
        __threadfence();
        unsigned int old2 = atomicAdd(gctr, 1u);
        if (old2 == NCHUNKS_TOTAL - 1) {
            float total = atomicAdd(acc, 0.0f);   // coherent read of final sum
            out[0] = total * (1.0f / (float)NPTS);
        }
    }
}

extern "C" void kernel_launch(void* const* d_in, const int* in_sizes, int n_in,
                              void* d_out, int out_size, void* d_ws, size_t ws_size,
                              hipStream_t stream)
{
    const float* src = (const float*)d_in[0];
    const float* tgt = (const float*)d_in[1];
    float* out = (float*)d_out;

    unsigned int* mins = (unsigned int*)d_ws;
    float*        acc  = (float*)(mins + NMINS);
    unsigned int* cctr = (unsigned int*)(acc + 1);
    unsigned int* gctr = cctr + NCHUNKS_TOTAL;

    // mins -> +inf pattern (0xFF... > any finite non-negative float bits)
    hipMemsetAsync(mins, 0xFF, (size_t)NMINS * sizeof(unsigned int), stream);
    // acc, chunk counters, global counter -> 0
    hipMemsetAsync(acc, 0, (1 + NCHUNKS_TOTAL + 1) * sizeof(unsigned int), stream);

    dim3 grid(2 * BATCH * NCHUNK * NSEG);   // 2048 blocks, 8/CU, 32 waves/CU
    chamfer_kernel<<<grid, TPB, 0, stream>>>(src, tgt, mins, acc, cctr, gctr, out);
}

// Round 3
// 106.804 us; speedup vs baseline: 1.0898x; 1.0898x over previous
//
#include <hip/hip_runtime.h>

// Chamfer distance, B=16, N=M=4096, D=3, fp32.
// loss = (sum of all 2*16*4096 directional min-d2) / 4096
// d2 = 2*( f + (e - s.t) ),  f=0.5|s|^2, e=0.5|t|^2
// Inner: per pair 3 v_fma_f32 (negation via src modifier) + 1/2 v_min3_f32
//        = 3.5 VALU ops/pair -> ~24 us floor at 78.6 T lane-ops/s.
// Register budget: __launch_bounds__(256,4) -> 128 VGPR cap; live set ~58.
// 2 dispatches total: one 0xFF memset (mins + tickets), one fused kernel.
// Tickets start at 0xFFFFFFFF: last of NSEG arrivals sees old == NSEG-2.

#define BATCH   16
#define NPTS    4096
#define TPB     256
#define PPT     8                     // query points per thread
#define CHUNK   (PPT * TPB)           // 2048
#define NCHUNK  (NPTS / CHUNK)        // 2
#define SEG     256                   // target points staged per block
#define NSEG    (NPTS / SEG)          // 16
#define NCHUNKS_TOTAL (2 * BATCH * NCHUNK)   // 64
#define NMINS   (2 * BATCH * NPTS)    // 131072

__global__ __launch_bounds__(TPB, 4) void chamfer_kernel(
    const float* __restrict__ src, const float* __restrict__ tgt,
    unsigned int* __restrict__ mins,
    unsigned int* __restrict__ cctr, unsigned int* __restrict__ gctr,
    float* __restrict__ partials, float* __restrict__ out)
{
    __shared__ float4 sh[SEG];        // (x, y, z, 0.5*|t|^2)
    __shared__ int islast;
    __shared__ float wsum[TPB / 64];

    int bx = blockIdx.x;
    const int seg   = bx & (NSEG - 1);   bx >>= 4;
    const int chunk = bx & (NCHUNK - 1); bx >>= 1;
    const int b     = bx & (BATCH - 1);  bx >>= 4;
    const int dir   = bx;

    const float* Abase = (dir ? tgt : src) + (size_t)b * NPTS * 3;  // queries
    const float* Bbase = (dir ? src : tgt) + (size_t)b * NPTS * 3;  // targets

    const int t = threadIdx.x;

    // Stage SEG target points with precomputed 0.5*|t|^2 (1 per thread).
    {
        int p = seg * SEG + t;
        float x = Bbase[3 * p + 0];
        float y = Bbase[3 * p + 1];
        float z = Bbase[3 * p + 2];
        sh[t] = make_float4(x, y, z, 0.5f * (x * x + y * y + z * z));
    }

    // Load PPT query points per thread (stride TPB, coalesced).
    float qx[PPT], qy[PPT], qz[PPT], f[PPT], mn[PPT];
#pragma unroll
    for (int k = 0; k < PPT; k++) {
        int p = chunk * CHUNK + k * TPB + t;
        float x = Abase[3 * p + 0];
        float y = Abase[3 * p + 1];
        float z = Abase[3 * p + 2];
        qx[k] = x; qy[k] = y; qz[k] = z;
        f[k] = 0.5f * (x * x + y * y + z * z);
        mn[k] = 1e30f;
    }

    __syncthreads();

    // Inner loop: 2 targets / iteration. Per k: 6 fma + 1 min3.
    for (int m = 0; m < SEG; m += 2) {
        float4 q0 = sh[m + 0];
        float4 q1 = sh[m + 1];
#pragma unroll
        for (int k = 0; k < PPT; k++) {
            float a0 = fmaf(-qx[k], q0.x, fmaf(-qy[k], q0.y, fmaf(-qz[k], q0.z, q0.w)));
            float a1 = fmaf(-qx[k], q1.x, fmaf(-qy[k], q1.y, fmaf(-qz[k], q1.z, q1.w)));
            mn[k] = fminf(fminf(a0, a1), mn[k]);   // v_min3_f32
        }
    }

    // Epilogue: finalize d2 (monotone transform commutes with min), merge.
    const int minsBase = ((dir * BATCH + b) * NPTS) + chunk * CHUNK;
#pragma unroll
    for (int k = 0; k < PPT; k++) {
        float d2 = fmaxf(2.0f * (mn[k] + f[k]), 0.0f);
        atomicMin(&mins[minsBase + k * TPB + t], __float_as_uint(d2));
    }

    __syncthreads();   // this block's atomics drained (vmcnt) before ticket

    const int cid = (dir * BATCH + b) * NCHUNK + chunk;
    if (t == 0) {
        __threadfence();
        unsigned int old = atomicAdd(&cctr[cid], 1u);   // init 0xFFFFFFFF
        islast = (old == (unsigned int)(NSEG - 2));
    }
    __syncthreads();
    if (!islast) return;

    // Last seg-block for this chunk: coherent readback of final mins, sum.
    float s = 0.0f;
#pragma unroll
    for (int k = 0; k < PPT; k++) {
        unsigned int v = atomicMin(&mins[minsBase + k * TPB + t], 0xFFFFFFFFu);
        s += __uint_as_float(v);
    }
#pragma unroll
    for (int off = 32; off > 0; off >>= 1) s += __shfl_down(s, off, 64);
    if ((t & 63) == 0) wsum[t >> 6] = s;
    __syncthreads();
    if (t == 0) {
        float blocksum = wsum[0] + wsum[1] + wsum[2] + wsum[3];
        atomicExch(&partials[cid], blocksum);           // device-scope store
        __threadfence();
        unsigned int old2 = atomicAdd(gctr, 1u);        // init 0xFFFFFFFF
        islast = (old2 == (unsigned int)(NCHUNKS_TOTAL - 2));
    }
    __syncthreads();
    if (!islast) return;

    // Globally-last chunk-winner: parallel coherent read of all partials.
    float p = 0.0f;
    if (t < NCHUNKS_TOTAL) p = atomicAdd(&partials[t], 0.0f);
#pragma unroll
    for (int off = 32; off > 0; off >>= 1) p += __shfl_down(p, off, 64);
    if ((t & 63) == 0) wsum[t >> 6] = p;
    __syncthreads();
    if (t == 0) {
        float total = wsum[0] + wsum[1] + wsum[2] + wsum[3];
        out[0] = total * (1.0f / (float)NPTS);
    }
}

extern "C" void kernel_launch(void* const* d_in, const int* in_sizes, int n_in,
                              void* d_out, int out_size, void* d_ws, size_t ws_size,
                              hipStream_t stream)
{
    const float* src = (const float*)d_in[0];
    const float* tgt = (const float*)d_in[1];
    float* out = (float*)d_out;

    unsigned int* mins     = (unsigned int*)d_ws;
    unsigned int* cctr     = mins + NMINS;                 // [NCHUNKS_TOTAL]
    unsigned int* gctr     = cctr + NCHUNKS_TOTAL;         // [1]
    float*        partials = (float*)(gctr + 1);           // [NCHUNKS_TOTAL]

    // One memset: mins -> +inf pattern (0xFF > any non-negative float bits),
    // tickets -> 0xFFFFFFFF (handled by wraparound compare). partials are
    // written with atomicExch before any read -> no init needed.
    hipMemsetAsync(mins, 0xFF, (size_t)(NMINS + NCHUNKS_TOTAL + 1) * sizeof(unsigned int), stream);

    dim3 grid(2 * BATCH * NCHUNK * NSEG);   // 1024 blocks, 4/CU
    chamfer_kernel<<<grid, TPB, 0, stream>>>(src, tgt, mins, cctr, gctr, partials, out);
}